// Round 5
// baseline (473.758 us; speedup 1.0000x reference)
//
#include <hip/hip_runtime.h>
#include <hip/hip_bf16.h>

typedef __bf16 bf16x8 __attribute__((ext_vector_type(8)));
typedef float floatx4 __attribute__((ext_vector_type(4)));

#define KDIM 2048
#define MDIM 512
#define HWDIM 4096
#define BN 128
#define BM 128
#define BK 32
#define NITER (KDIM / BK)   // 64

// Prologue: Wc[o][c] = (bf16) W[o][c][0][4].
// Coalesced float4 reads of all of W; float index f is a center tap iff f%9==4.
__global__ void extract_w_kernel(const float* __restrict__ W, __bf16* __restrict__ Wc) {
  const int idx = blockIdx.x * 256 + threadIdx.x;
  const float4 v = ((const float4*)W)[idx];
  const float vv[4] = {v.x, v.y, v.z, v.w};
  const int f0 = idx * 4;
#pragma unroll
  for (int j = 0; j < 4; ++j) {
    const int f = f0 + j;
    if (f % 9 == 4) Wc[f / 9] = (__bf16)vv[j];
  }
}

// 1024 blocks (4 per CU) = 256 N-tiles (8 img x 32 nb, BN=128) x 4 M-quarters
// (BM=128). 256 threads = 4 waves; wave w owns M rows [mq*128 + 32w, +32),
// acc[2][8] = 64 VGPR. G=4 independent barrier groups per CU: while one
// block drains its __syncthreads vmcnt(0), three others compute (R4's G=2
// left a 3x gap between measured 5475 cy/iter and the 1730 cy resource floor).
// XCD swizzle: all 4 M-quarters of one N-tile on the same XCD, consecutive
// slots -> fea panel fetched once from HBM + 3 L2 hits. A traffic 512 MB.
// B: double-buffered LDS (128 hw x 32 k bf16, 2 x 8 KB), staged by all 4
// waves as two half-tiles (h0 = k 0..15, h1 = k 16..31) with staggered
// depth-1.5 prefetch: landing set issued in body i, written in body i+1
// (one full body in flight > HBM latency), 16 landing VGPRs total.
// Swizzle (4 granules of 8 bf16 per 64 B row): phys = (g + (hw>>1)) & 3 ->
// uniform accesses on both ds_write_b128 and ds_read_b128 (0 conflicts, R4).
__global__ __launch_bounds__(256, 4) void conv1x1_kernel(
    const float* __restrict__ fea, const __bf16* __restrict__ Wc,
    const float* __restrict__ bias, float* __restrict__ out) {
  __shared__ __align__(16) __bf16 Bs[2][BN * BK];   // 2 x 8 KB

  const int t    = threadIdx.x;
  const int wave = t >> 6;        // 0..3
  const int lane = t & 63;
  const int l15  = lane & 15;
  const int quad = lane >> 4;

  // XCD-grouped decode: 8 xcds x 128 slots; 4 consecutive slots = 4 M-quarters
  const int xcd  = blockIdx.x & 7;
  const int slot = blockIdx.x >> 3;           // 0..127
  const int tile = xcd * 32 + (slot >> 2);    // 0..255
  const int mq   = slot & 3;
  const int img  = tile >> 5;
  const int nb   = tile & 31;

  const int wm = mq * BM + wave * 32;         // M rows [wm, wm+32)

  const float* feaN = fea + (size_t)img * KDIM * HWDIM + (size_t)nb * BN;
  float*       outN = out + (size_t)img * MDIM * HWDIM + (size_t)nb * BN;

  // ---- B staging: thread covers hw = t&127, k-octet kg = t>>7 in each half ----
  const int hw = t & 127;
  const int kg = t >> 7;                      // 0..1
  // h0: logical granule kg   (k = 8kg   + [0,8));  h1: granule 2+kg (k = 16+8kg + [0,8))
  const int b0 = hw * BK + (((kg     + (hw >> 1)) & 3) * 8);
  const int b1 = hw * BK + (((2 + kg + (hw >> 1)) & 3) * 8);
  const float* src0 = feaN + (size_t)(kg * 8) * HWDIM + hw;
  const float* src1 = feaN + (size_t)(16 + kg * 8) * HWDIM + hw;

  // ---- A: direct global loads from Wc (L2/L3-resident) ----
  const __bf16* aptr = Wc + (size_t)(wm + l15) * KDIM + quad * 8;

  float pfa[8], pfb[8];   // two 8-reg landing sets (staggered half-tile prefetch)
  floatx4 acc[2][8];      // mt x nt
#pragma unroll
  for (int i = 0; i < 2; ++i)
#pragma unroll
    for (int j = 0; j < 8; ++j) acc[i][j] = (floatx4){0.f, 0.f, 0.f, 0.f};

  // ---- prologue: load+write tile 0; issue tile 1 into landing sets ----
#pragma unroll
  for (int j = 0; j < 8; ++j) pfa[j] = src0[(size_t)j * HWDIM];
#pragma unroll
  for (int j = 0; j < 8; ++j) pfb[j] = src1[(size_t)j * HWDIM];
  {
    bf16x8 h0, h1;
#pragma unroll
    for (int j = 0; j < 8; ++j) h0[j] = (__bf16)pfa[j];
#pragma unroll
    for (int j = 0; j < 8; ++j) h1[j] = (__bf16)pfb[j];
    *(bf16x8*)&Bs[0][b0] = h0;
    *(bf16x8*)&Bs[0][b1] = h1;
  }
#pragma unroll
  for (int j = 0; j < 8; ++j) pfa[j] = src0[(size_t)(BK + j) * HWDIM];
#pragma unroll
  for (int j = 0; j < 8; ++j) pfb[j] = src1[(size_t)(BK + j) * HWDIM];
  __syncthreads();

  // Body (CUR = i&1, compile-time):
  //  1) A-frag loads (L2/L3)
  //  2) write h0(i+1) from pfa; re-issue pfa <- h0(i+2)
  //  3) write h1(i+1) from pfb; re-issue pfb <- h1(i+2)
  //  4) ds_read B frags + MFMA
  //  5) __syncthreads (4 blocks/CU cover each other's drain)
#define KBODY(I, CUR)                                                          \
  {                                                                            \
    const int i_ = (I);                                                        \
    bf16x8 af[2];                                                              \
    const __bf16* ap = aptr + (size_t)i_ * BK;                                 \
    _Pragma("unroll")                                                          \
    for (int mt = 0; mt < 2; ++mt)                                             \
      af[mt] = *(const bf16x8*)(ap + (size_t)(mt * 16) * KDIM);                \
    if (i_ + 1 < NITER) {                                                      \
      bf16x8 hn;                                                               \
      _Pragma("unroll")                                                        \
      for (int j = 0; j < 8; ++j) hn[j] = (__bf16)pfa[j];                      \
      *(bf16x8*)&Bs[(CUR) ^ 1][b0] = hn;                                       \
    }                                                                          \
    if (i_ + 2 < NITER) {                                                      \
      const float* p = src0 + (size_t)(i_ + 2) * BK * HWDIM;                   \
      _Pragma("unroll")                                                        \
      for (int j = 0; j < 8; ++j) pfa[j] = p[(size_t)j * HWDIM];               \
    }                                                                          \
    if (i_ + 1 < NITER) {                                                      \
      bf16x8 hn;                                                               \
      _Pragma("unroll")                                                        \
      for (int j = 0; j < 8; ++j) hn[j] = (__bf16)pfb[j];                      \
      *(bf16x8*)&Bs[(CUR) ^ 1][b1] = hn;                                       \
    }                                                                          \
    if (i_ + 2 < NITER) {                                                      \
      const float* p = src1 + (size_t)(i_ + 2) * BK * HWDIM;                   \
      _Pragma("unroll")                                                        \
      for (int j = 0; j < 8; ++j) pfb[j] = p[(size_t)j * HWDIM];               \
    }                                                                          \
    _Pragma("unroll")                                                          \
    for (int nt = 0; nt < 8; ++nt) {                                           \
      const int n_ = nt * 16 + l15;                                            \
      const bf16x8 bfr = *(const bf16x8*)&Bs[(CUR)][n_ * BK +                  \
                            (((quad + (n_ >> 1)) & 3) * 8)];                   \
      _Pragma("unroll")                                                        \
      for (int mt = 0; mt < 2; ++mt)                                           \
        acc[mt][nt] = __builtin_amdgcn_mfma_f32_16x16x32_bf16(af[mt], bfr,     \
                          acc[mt][nt], 0, 0, 0);                               \
    }                                                                          \
    __syncthreads();                                                           \
  }

  for (int i = 0; i < NITER; i += 2) {
    KBODY(i, 0)
    KBODY(i + 1, 1)
  }
#undef KBODY

  // Epilogue: bias + relu  (C/D: col = l15, row = quad*4 + r — verified)
#pragma unroll
  for (int mt = 0; mt < 2; ++mt) {
    const int o0 = wm + mt * 16 + quad * 4;
    const float4 bv = *(const float4*)(bias + o0);
    const float bvr[4] = {bv.x, bv.y, bv.z, bv.w};
#pragma unroll
    for (int r = 0; r < 4; ++r) {
      const size_t ro = (size_t)(o0 + r) * HWDIM;
#pragma unroll
      for (int nt = 0; nt < 8; ++nt) {
        float x = acc[mt][nt][r] + bvr[r];
        x = x > 0.f ? x : 0.f;
        __builtin_nontemporal_store(x, &outN[ro + nt * 16 + l15]);
      }
    }
  }
}

extern "C" void kernel_launch(void* const* d_in, const int* in_sizes, int n_in,
                              void* d_out, int out_size, void* d_ws, size_t ws_size,
                              hipStream_t stream) {
  const float* fea  = (const float*)d_in[0];
  const float* W    = (const float*)d_in[1];
  const float* bias = (const float*)d_in[2];
  float* out = (float*)d_out;
  __bf16* Wc = (__bf16*)d_ws;   // 2 MB scratch

  // 512*2048*9 floats / 4 per thread / 256 per block = 9216 blocks (exact)
  hipLaunchKernelGGL(extract_w_kernel, dim3(9216), dim3(256), 0, stream, W, Wc);
  hipLaunchKernelGGL(conv1x1_kernel, dim3(1024), dim3(256), 0, stream, fea, Wc, bias, out);
}